// Round 8
// baseline (246.593 us; speedup 1.0000x reference)
//
#include <hip/hip_runtime.h>

#define BATCH 512
#define SEQ   512
#define VOCAB 1000
#define EMB   100
#define UNITS 64

// ---------------------------------------------------------------------------
// Kernel 1: P[v][u] = sum_d emb[v][d] * Wxh[d][u] + b[u]   (VOCAB x UNITS)
// ---------------------------------------------------------------------------
__global__ __launch_bounds__(64) void proj_kernel(
    const float* __restrict__ emb, const float* __restrict__ Wxh,
    const float* __restrict__ bias, float* __restrict__ P) {
  const int v = blockIdx.x;
  const int u = threadIdx.x;
  const float* e = emb + v * EMB;
  float acc = bias[u];
#pragma unroll 5
  for (int d = 0; d < EMB; ++d) acc += e[d] * Wxh[d * UNITS + u];
  P[v * UNITS + u] = acc;
}

// Broadcast lane k's h to an SGPR (wave-uniform value).
#define RL(k) __int_as_float(__builtin_amdgcn_readlane(__float_as_int(h), (k)))

// 16 units of the dot: 16 independent readlanes -> one asm "gate" that
// redefines all 16 values (so no fmac can be scheduled before ALL 16
// readlanes have issued) -> 16 fmacs onto 8 accumulators.
// This forces >=16-wide separation between each readlane and its consumer,
// killing the SGPR-write->VALU-read hazard pairing that made r4 cost
// ~9 cyc/unit. Blocks pipeline: block k's fmacs overlap block k+1's
// readlanes (independent).
#define DOT16(B)                                                            \
  do {                                                                      \
    float b0 = RL(B + 0), b1 = RL(B + 1), b2 = RL(B + 2), b3 = RL(B + 3);   \
    float b4 = RL(B + 4), b5 = RL(B + 5), b6 = RL(B + 6), b7 = RL(B + 7);   \
    float b8 = RL(B + 8), b9 = RL(B + 9), b10 = RL(B + 10),                 \
          b11 = RL(B + 11);                                                 \
    float b12 = RL(B + 12), b13 = RL(B + 13), b14 = RL(B + 14),             \
          b15 = RL(B + 15);                                                 \
    asm volatile("" : "+s"(b0), "+s"(b1), "+s"(b2), "+s"(b3), "+s"(b4),     \
                      "+s"(b5), "+s"(b6), "+s"(b7), "+s"(b8), "+s"(b9),     \
                      "+s"(b10), "+s"(b11), "+s"(b12), "+s"(b13),           \
                      "+s"(b14), "+s"(b15));                                \
    a0 += b0 * wh[B + 0];                                                   \
    a1 += b1 * wh[B + 1];                                                   \
    a2 += b2 * wh[B + 2];                                                   \
    a3 += b3 * wh[B + 3];                                                   \
    a4 += b4 * wh[B + 4];                                                   \
    a5 += b5 * wh[B + 5];                                                   \
    a6 += b6 * wh[B + 6];                                                   \
    a7 += b7 * wh[B + 7];                                                   \
    a0 += b8 * wh[B + 8];                                                   \
    a1 += b9 * wh[B + 9];                                                   \
    a2 += b10 * wh[B + 10];                                                 \
    a3 += b11 * wh[B + 11];                                                 \
    a4 += b12 * wh[B + 12];                                                 \
    a5 += b13 * wh[B + 13];                                                 \
    a6 += b14 * wh[B + 14];                                                 \
    a7 += b15 * wh[B + 15];                                                 \
  } while (0)

// ---------------------------------------------------------------------------
// Kernel 2: sequential scan, one wave per batch row, lane j = unit j.
//   h[j] <- tanh(P[tok_t][j] + sum_i h[i]*Whh[i][j])
//
// r7 post-mortem: LDS-broadcast floor is ~480 cyc/step (write-visibility +
// read latency + 16x b128 DS service); measured 571-619. This version drops
// LDS entirely: h broadcast via 64 v_readlane into SGPRs (no memory
// latency), gated in blocks of 16 by multi-operand asm so the scheduler
// cannot pair each readlane with its fmac (r4's 9-cyc/unit hazard mode).
// Issue floor ~280-330 cyc/step.
// ---------------------------------------------------------------------------
__global__ __launch_bounds__(64)
__attribute__((amdgpu_waves_per_eu(1, 1)))
void scan_kernel(
    const int* __restrict__ tok, const float* __restrict__ P,
    const float* __restrict__ Whh, const float* __restrict__ Wout,
    const float* __restrict__ bout, float* __restrict__ out) {
  const int row  = blockIdx.x;
  const int lane = threadIdx.x;

  // Whh column for this lane: wh[i] = Whh[i][lane], pinned in VGPRs
  // (r4 proved waves_per_eu(1,1) + pins keep these resident, VGPR=132).
  float wh[UNITS];
#pragma unroll
  for (int i = 0; i < UNITS; ++i) {
    float w = Whh[i * UNITS + lane];
    asm volatile("" : "+v"(w));
    wh[i] = w;
  }

  // All 512 tokens of this row, pre-scaled by UNITS (coalesced loads).
  int tokv[SEQ / 64];
  const int* trow = tok + (long)row * SEQ;
#pragma unroll
  for (int c = 0; c < SEQ / 64; ++c) {
    int t = trow[c * 64 + lane] * UNITS;
    asm volatile("" : "+v"(t));
    tokv[c] = t;
  }

  float h = 0.f;

  // Prefetch P row for t=0.
  int tk0 = __builtin_amdgcn_readlane(tokv[0], 0);
  float a = P[(long)tk0 + lane];

#pragma unroll
  for (int c = 0; c < SEQ / 64; ++c) {
#pragma unroll 2
    for (int tt = 0; tt < 64; ++tt) {
      float a_cur = a;
      // Prefetch next timestep's P row (L2-hit ~200 cyc, consumed one full
      // step later — covered).
      int ntt = (tt + 1) & 63;
      int tkn = __builtin_amdgcn_readlane(tokv[c], ntt);
      a = P[(long)tkn + lane];

      // s = a_cur + sum_i h_i * wh_i via 4 gated blocks of 16.
      float a0 = a_cur, a1 = 0.f, a2 = 0.f, a3 = 0.f;
      float a4 = 0.f, a5 = 0.f, a6 = 0.f, a7 = 0.f;
      DOT16(0);
      DOT16(16);
      DOT16(32);
      DOT16(48);
      float s = ((a0 + a1) + (a2 + a3)) + ((a4 + a5) + (a6 + a7));

      // tanh(s) = 1 - 2/(exp(2s)+1)  (safe at both extremes)
      float e = __expf(2.f * s);
      h = 1.f - 2.f / (e + 1.f);
    }
    if (c + 1 < SEQ / 64) {
      int tkb = __builtin_amdgcn_readlane(tokv[c + 1], 0);
      a = P[(long)tkb + lane];
    }
  }

  // out[row] = sigmoid(sum_j h[j]*Wout[j] + bout)
  float p = h * Wout[lane];
#pragma unroll
  for (int off = 32; off > 0; off >>= 1) p += __shfl_xor(p, off);
  if (lane == 0) out[row] = 1.f / (1.f + __expf(-(p + bout[0])));
}

extern "C" void kernel_launch(void* const* d_in, const int* in_sizes, int n_in,
                              void* d_out, int out_size, void* d_ws, size_t ws_size,
                              hipStream_t stream) {
  const int*   tok  = (const int*)  d_in[0];  // [BATCH, SEQ] int32
  const float* emb  = (const float*)d_in[1];  // [VOCAB, EMB]
  const float* Wxh  = (const float*)d_in[2];  // [EMB, UNITS]
  const float* Whh  = (const float*)d_in[3];  // [UNITS, UNITS]
  const float* bias = (const float*)d_in[4];  // [UNITS]
  const float* Wout = (const float*)d_in[5];  // [UNITS, 1]
  const float* bout = (const float*)d_in[6];  // [1]
  float* out = (float*)d_out;                 // [BATCH, 1] fp32

  float* P = (float*)d_ws;                    // VOCAB*UNITS fp32 = 256 KB

  proj_kernel<<<VOCAB, 64, 0, stream>>>(emb, Wxh, bias, P);
  scan_kernel<<<BATCH, 64, 0, stream>>>(tok, P, Whh, Wout, bout, out);
}

// Round 10
// 201.865 us; speedup vs baseline: 1.2216x; 1.2216x over previous
//
#include <hip/hip_runtime.h>

#define BATCH 512
#define SEQ   512
#define VOCAB 1000
#define EMB   100
#define UNITS 64

typedef float v2f __attribute__((ext_vector_type(2)));

// ---------------------------------------------------------------------------
// Kernel 1: P[v][u] = sum_d emb[v][d] * Wxh[d][u] + b[u]   (VOCAB x UNITS)
// ---------------------------------------------------------------------------
__global__ __launch_bounds__(64) void proj_kernel(
    const float* __restrict__ emb, const float* __restrict__ Wxh,
    const float* __restrict__ bias, float* __restrict__ P) {
  const int v = blockIdx.x;
  const int u = threadIdx.x;
  const float* e = emb + v * EMB;
  float acc = bias[u];
#pragma unroll 5
  for (int d = 0; d < EMB; ++d) acc += e[d] * Wxh[d * UNITS + u];
  P[v * UNITS + u] = acc;
}

// ---------------------------------------------------------------------------
// Kernel 2: sequential scan, one wave per batch row, lane j = unit j.
//   h[j] <- tanh(P[tok_t][j] + sum_i h[i]*Whh[i][j])
//
// Evidence: readlane broadcast = ~13 cyc/unit intrinsic (r4==r8) — dead end.
// Compiler-scheduled LDS broadcast = 571 cyc/step (r5; read/consume round
// trips; r7's source-level split was re-fused). This version hand-schedules
// the LDS phase: publish + 32 broadcast ds_read_b64 issued back-to-back,
// stepped s_waitcnt lgkmcnt(N) consume blocks overlapping the drain.
// r9 compile fix: DS address operands must be single 32-bit VGPRs — pass
// (unsigned)(uintptr_t)lds_ptr, not the 64-bit generic pointer.
// ---------------------------------------------------------------------------
__global__ __launch_bounds__(64)
__attribute__((amdgpu_waves_per_eu(1, 1)))
void scan_kernel(
    const int* __restrict__ tok, const float* __restrict__ P,
    const float* __restrict__ Whh, const float* __restrict__ Wout,
    const float* __restrict__ bout, float* __restrict__ out) {
  const int row  = blockIdx.x;
  const int lane = threadIdx.x;

  __shared__ __align__(16) float hsf[UNITS];  // h broadcast buffer (256 B)

  // Whh columns for this lane as 32 packed pairs, pinned in VGPRs.
  v2f wh2[UNITS / 2];
#pragma unroll
  for (int k = 0; k < UNITS / 2; ++k) {
    float wx = Whh[(2 * k + 0) * UNITS + lane];
    float wy = Whh[(2 * k + 1) * UNITS + lane];
    asm volatile("" : "+v"(wx), "+v"(wy));
    wh2[k].x = wx;
    wh2[k].y = wy;
  }

  // All 512 tokens of this row, pre-scaled by UNITS (coalesced loads).
  int tokv[SEQ / 64];
  const int* trow = tok + (long)row * SEQ;
#pragma unroll
  for (int c = 0; c < SEQ / 64; ++c) {
    int t = trow[c * 64 + lane] * UNITS;
    asm volatile("" : "+v"(t));
    tokv[c] = t;
  }

  // h_0 = 0 (single wave; in-order DS pipe, no barriers needed anywhere).
  hsf[lane] = 0.f;

  // 32-bit LDS byte addresses for the asm DS ops (low 32 bits of the
  // shared-aperture flat address are the LDS offset).
  const unsigned wa  = (unsigned)(uintptr_t)(hsf + lane);  // publish slot
  const unsigned rba = (unsigned)(uintptr_t)hsf;           // broadcast base

  float h = 0.f;

  // Prefetch P row for t=0.
  int tk0 = __builtin_amdgcn_readlane(tokv[0], 0);
  float a = P[(long)tk0 + lane];

#pragma unroll
  for (int c = 0; c < SEQ / 64; ++c) {
#pragma unroll 2
    for (int tt = 0; tt < 64; ++tt) {
      float a_cur = a;
      // Prefetch next timestep's P row (global -> vmcnt, independent of the
      // lgkmcnt waits below; consumed a full step later).
      int ntt = (tt + 1) & 63;
      int tkn = __builtin_amdgcn_readlane(tokv[c], ntt);
      a = P[(long)tkn + lane];

      // ---- publish h, then stream all 32 broadcast reads ----
      v2f t0, t1, t2, t3, t4, t5, t6, t7, t8, t9, t10, t11, t12, t13, t14, t15;
      v2f u0, u1, u2, u3, u4, u5, u6, u7, u8, u9, u10, u11, u12, u13, u14, u15;
      asm volatile(
          "ds_write_b32 %[wa], %[hv]\n\t"
          "ds_read_b64 %[t0],  %[rb] offset:0\n\t"
          "ds_read_b64 %[t1],  %[rb] offset:8\n\t"
          "ds_read_b64 %[t2],  %[rb] offset:16\n\t"
          "ds_read_b64 %[t3],  %[rb] offset:24\n\t"
          "ds_read_b64 %[t4],  %[rb] offset:32\n\t"
          "ds_read_b64 %[t5],  %[rb] offset:40\n\t"
          "ds_read_b64 %[t6],  %[rb] offset:48\n\t"
          "ds_read_b64 %[t7],  %[rb] offset:56\n\t"
          "ds_read_b64 %[t8],  %[rb] offset:64\n\t"
          "ds_read_b64 %[t9],  %[rb] offset:72\n\t"
          "ds_read_b64 %[t10], %[rb] offset:80\n\t"
          "ds_read_b64 %[t11], %[rb] offset:88\n\t"
          "ds_read_b64 %[t12], %[rb] offset:96\n\t"
          "ds_read_b64 %[t13], %[rb] offset:104\n\t"
          "ds_read_b64 %[t14], %[rb] offset:112\n\t"
          "ds_read_b64 %[t15], %[rb] offset:120\n\t"
          : [t0] "=&v"(t0), [t1] "=&v"(t1), [t2] "=&v"(t2), [t3] "=&v"(t3),
            [t4] "=&v"(t4), [t5] "=&v"(t5), [t6] "=&v"(t6), [t7] "=&v"(t7),
            [t8] "=&v"(t8), [t9] "=&v"(t9), [t10] "=&v"(t10),
            [t11] "=&v"(t11), [t12] "=&v"(t12), [t13] "=&v"(t13),
            [t14] "=&v"(t14), [t15] "=&v"(t15)
          : [wa] "v"(wa), [hv] "v"(h), [rb] "v"(rba)
          : "memory");
      asm volatile(
          "ds_read_b64 %[u0],  %[rb] offset:128\n\t"
          "ds_read_b64 %[u1],  %[rb] offset:136\n\t"
          "ds_read_b64 %[u2],  %[rb] offset:144\n\t"
          "ds_read_b64 %[u3],  %[rb] offset:152\n\t"
          "ds_read_b64 %[u4],  %[rb] offset:160\n\t"
          "ds_read_b64 %[u5],  %[rb] offset:168\n\t"
          "ds_read_b64 %[u6],  %[rb] offset:176\n\t"
          "ds_read_b64 %[u7],  %[rb] offset:184\n\t"
          "ds_read_b64 %[u8],  %[rb] offset:192\n\t"
          "ds_read_b64 %[u9],  %[rb] offset:200\n\t"
          "ds_read_b64 %[u10], %[rb] offset:208\n\t"
          "ds_read_b64 %[u11], %[rb] offset:216\n\t"
          "ds_read_b64 %[u12], %[rb] offset:224\n\t"
          "ds_read_b64 %[u13], %[rb] offset:232\n\t"
          "ds_read_b64 %[u14], %[rb] offset:240\n\t"
          "ds_read_b64 %[u15], %[rb] offset:248\n\t"
          : [u0] "=&v"(u0), [u1] "=&v"(u1), [u2] "=&v"(u2), [u3] "=&v"(u3),
            [u4] "=&v"(u4), [u5] "=&v"(u5), [u6] "=&v"(u6), [u7] "=&v"(u7),
            [u8] "=&v"(u8), [u9] "=&v"(u9), [u10] "=&v"(u10),
            [u11] "=&v"(u11), [u12] "=&v"(u12), [u13] "=&v"(u13),
            [u14] "=&v"(u14), [u15] "=&v"(u15)
          : [rb] "v"(rba)
          : "memory");

      // ---- consume with stepped waits (in-order DS returns; first four
      //      waits capped at the 4-bit lgkmcnt max of 15) ----
      v2f acc0, acc1 = {0.f, 0.f}, acc2 = {0.f, 0.f}, acc3 = {0.f, 0.f};
      acc0.x = a_cur;
      acc0.y = 0.f;
#define BBLK(N, p0, p1, p2, p3, w0, w1, w2, w3)                              \
      asm volatile("s_waitcnt lgkmcnt(" #N ")\n\t"                           \
                   "v_pk_fma_f32 %[a0], %[x0], %[y0], %[a0]\n\t"             \
                   "v_pk_fma_f32 %[a1], %[x1], %[y1], %[a1]\n\t"             \
                   "v_pk_fma_f32 %[a2], %[x2], %[y2], %[a2]\n\t"             \
                   "v_pk_fma_f32 %[a3], %[x3], %[y3], %[a3]\n\t"             \
                   : [a0] "+v"(acc0), [a1] "+v"(acc1), [a2] "+v"(acc2),      \
                     [a3] "+v"(acc3)                                         \
                   : [x0] "v"(p0), [y0] "v"(w0), [x1] "v"(p1), [y1] "v"(w1), \
                     [x2] "v"(p2), [y2] "v"(w2), [x3] "v"(p3), [y3] "v"(w3))
      BBLK(15, t0, t1, t2, t3, wh2[0], wh2[1], wh2[2], wh2[3]);
      BBLK(15, t4, t5, t6, t7, wh2[4], wh2[5], wh2[6], wh2[7]);
      BBLK(15, t8, t9, t10, t11, wh2[8], wh2[9], wh2[10], wh2[11]);
      BBLK(15, t12, t13, t14, t15, wh2[12], wh2[13], wh2[14], wh2[15]);
      BBLK(12, u0, u1, u2, u3, wh2[16], wh2[17], wh2[18], wh2[19]);
      BBLK(8, u4, u5, u6, u7, wh2[20], wh2[21], wh2[22], wh2[23]);
      BBLK(4, u8, u9, u10, u11, wh2[24], wh2[25], wh2[26], wh2[27]);
      BBLK(0, u12, u13, u14, u15, wh2[28], wh2[29], wh2[30], wh2[31]);
#undef BBLK

      v2f rr = (acc0 + acc1) + (acc2 + acc3);
      float s = rr.x + rr.y;

      // tanh(s) = 1 - 2/(exp(2s)+1)  (safe at both extremes)
      float e = __expf(2.f * s);
      h = 1.f - 2.f / (e + 1.f);
    }
    if (c + 1 < SEQ / 64) {
      int tkb = __builtin_amdgcn_readlane(tokv[c + 1], 0);
      a = P[(long)tkb + lane];
    }
  }

  // out[row] = sigmoid(sum_j h[j]*Wout[j] + bout)
  float p = h * Wout[lane];
#pragma unroll
  for (int off = 32; off > 0; off >>= 1) p += __shfl_xor(p, off);
  if (lane == 0) out[row] = 1.f / (1.f + __expf(-(p + bout[0])));
}

extern "C" void kernel_launch(void* const* d_in, const int* in_sizes, int n_in,
                              void* d_out, int out_size, void* d_ws, size_t ws_size,
                              hipStream_t stream) {
  const int*   tok  = (const int*)  d_in[0];  // [BATCH, SEQ] int32
  const float* emb  = (const float*)d_in[1];  // [VOCAB, EMB]
  const float* Wxh  = (const float*)d_in[2];  // [EMB, UNITS]
  const float* Whh  = (const float*)d_in[3];  // [UNITS, UNITS]
  const float* bias = (const float*)d_in[4];  // [UNITS]
  const float* Wout = (const float*)d_in[5];  // [UNITS, 1]
  const float* bout = (const float*)d_in[6];  // [1]
  float* out = (float*)d_out;                 // [BATCH, 1] fp32

  float* P = (float*)d_ws;                    // VOCAB*UNITS fp32 = 256 KB

  proj_kernel<<<VOCAB, 64, 0, stream>>>(emb, Wxh, bias, P);
  scan_kernel<<<BATCH, 64, 0, stream>>>(tok, P, Whh, Wout, bout, out);
}